// Round 1
// baseline (386.788 us; speedup 1.0000x reference)
//
#include <hip/hip_runtime.h>

// ---------------------------------------------------------------------------
// Self-attention, fp16-MFMA pipeline.
// R6: pipelined GEMM core (T3+T4+T5 from the catalog) replacing the
// 2-barrier-per-K-tile m97 structure:
//   - 256x128 tile, BK=64, 512 threads = 8 waves (4 row-waves x 2 col-waves),
//     per-wave 64x64 output (4x4 MFMA tiles of 16x16x32_f16).
//   - 3-deep LDS ring: 3 x (A 256x64 + B 128x64) f16 = 144 KB, 1 block/CU.
//     Staging runs TWO K-tiles ahead: tile t+2 is issued into the buffer that
//     held tile t-1 (fully consumed before the boundary barrier of tile t, so
//     no same-buffer write-while-read hazards).
//   - Per K-tile boundary: s_waitcnt vmcnt(6) (tile t+1's 6 loads stay in
//     flight across the barrier -- never drain to 0 in steady state) + one
//     raw s_barrier.  Last tile uses vmcnt(0).
//   - s_setprio(1) around each 16-MFMA cluster.
//   - XOR swizzle retained from R5: LDS row r, 16B-chunk c holds global chunk
//     c ^ (r&7); applied on staging SOURCE address (global_load_lds dest must
//     stay lane-contiguous) and on fragment reads. 0 bank conflicts measured.
//
// Pipeline invariants (nt = K/64 tiles):
//   prologue: stage t0, t1 (6 loads each).
//   iter t:   vmcnt(6 if t+1<nt else 0); s_barrier;
//             stage t+2 into buf (t+2)%3 if t+2<nt;
//             compute tile t from buf t%3 (2 kk-chunks x 16 MFMA).
//   FIFO vmcnt retire => at the boundary of tile t everything except tile
//   t+1's 6 loads has landed, i.e. tile t is resident.
// ---------------------------------------------------------------------------

typedef _Float16 f16;
typedef _Float16 f16x8 __attribute__((ext_vector_type(8)));
typedef _Float16 f16x4 __attribute__((ext_vector_type(4)));
typedef float f32x4 __attribute__((ext_vector_type(4)));

__device__ __forceinline__ void gload16(const void* g, void* l) {
    __builtin_amdgcn_global_load_lds((__attribute__((address_space(1))) void*)g,
                                     (__attribute__((address_space(3))) void*)l,
                                     16, 0, 0);
}

// MODE 0: C[row,col] = (OutT)acc
// MODE 1: C = f16(exp(acc/8 - 12)); atomicAdd row sums into R[bz*2048+row]
// MODE 2: C = (OutT)(acc / R[bz*2048+row])
template <int MODE, typename OutT>
__global__ __launch_bounds__(512, 2)
void gemm_bt(const f16* __restrict__ A, const f16* __restrict__ B,
             OutT* __restrict__ C, float* R, int K, int lda, int ldb, int ldc,
             long sA, long sB, long sC)
{
    __shared__ __align__(16) f16 lA[3 * 16384];   // 3 bufs x [256][64]
    __shared__ __align__(16) f16 lB[3 * 8192];    // 3 bufs x [128][64]

    const int tid  = threadIdx.x;
    const int wave = tid >> 6;
    const int lane = tid & 63;

    // XCD-aware remap (bijection when nb % 8 == 0; all our grids qualify)
    const unsigned gx = gridDim.x, gy = gridDim.y;
    const unsigned nb = gx * gy * gridDim.z;
    unsigned lin = blockIdx.x + gx * (blockIdx.y + gy * blockIdx.z);
    if ((nb & 7u) == 0u) lin = (lin & 7u) * (nb >> 3) + (lin >> 3);
    const unsigned bx = lin % gx;
    const unsigned rem = lin / gx;
    const unsigned by = rem % gy;
    const unsigned bz = rem / gy;

    A += (long)bz * sA;
    B += (long)bz * sB;
    C += (long)bz * sC;

    const long row0 = (long)by * 256;
    const long col0 = (long)bx * 128;

    // Staging: 512 threads, pass p covers rows p*64 + (tid>>3), dst 16B-chunk
    // tid&7; swizzled SOURCE chunk = (tid&7) ^ (row&7) (row&7 == (tid>>3)&7,
    // independent of p). LDS dst = base + p*4096 + tid*8 f16 (lane-linear).
    const int r0 = tid >> 3;                       // 0..63
    const int cs = (((tid & 7) ^ (r0 & 7)) * 8);   // swizzled source col (f16)
    const f16* ag0 = A + (row0 +       r0) * lda + cs;
    const f16* ag1 = A + (row0 +  64 + r0) * lda + cs;
    const f16* ag2 = A + (row0 + 128 + r0) * lda + cs;
    const f16* ag3 = A + (row0 + 192 + r0) * lda + cs;
    const f16* bg0 = B + (col0 +       r0) * ldb + cs;
    const f16* bg1 = B + (col0 +  64 + r0) * ldb + cs;

#define STAGE(dA, dB) do {                                                    \
        gload16(ag0, (dA) +         tid * 8);                                 \
        gload16(ag1, (dA) +  4096 + tid * 8);                                 \
        gload16(ag2, (dA) +  8192 + tid * 8);                                 \
        gload16(ag3, (dA) + 12288 + tid * 8);                                 \
        gload16(bg0, (dB) +         tid * 8);                                 \
        gload16(bg1, (dB) +  4096 + tid * 8);                                 \
        ag0 += 64; ag1 += 64; ag2 += 64; ag3 += 64; bg0 += 64; bg1 += 64;     \
    } while (0)

    // 8 waves in 4x2 -> each wave owns 64x64 = 4x4 MFMA tiles of 16x16.
    const int wm = wave >> 1, wn = wave & 1;
    const int fl = lane & 15;            // m (A) / n (B) within tile
    const int q  = lane >> 4;            // k-chunk within 32-k half
    // fragment read: row*64 + ((g ^ (row&7)) * 8); row&7 == fl&7 (tile rows
    // are multiples of 16).  kk=0: g=q -> co; kk=32: g=q^4 -> co^32.
    const int co = ((q ^ (fl & 7)) * 8);

    f32x4 acc[4][4] = {};
    const int nt = K >> 6;

    // Prologue: stage tiles 0 and 1 into bufs 0 and 1 (12 loads in flight).
    STAGE(lA, lB);
    if (nt > 1) STAGE(lA + 16384, lB + 8192);

    int cb = 0;                           // buffer holding tile t (t % 3)
    for (int t = 0; t < nt; ++t) {
        // Boundary: tile t resident once all but tile t+1's 6 loads retire.
        if (t + 1 < nt) { asm volatile("s_waitcnt vmcnt(6)" ::: "memory"); }
        else            { asm volatile("s_waitcnt vmcnt(0)" ::: "memory"); }
        __builtin_amdgcn_s_barrier();

        // Stage tile t+2 into buf (t+2)%3 == (cb+2)%3 (held tile t-1; all its
        // reads completed before the barrier we just crossed).
        const int nb2 = cb ? cb - 1 : 2;
        if (t + 2 < nt) STAGE(lA + nb2 * 16384, lB + nb2 * 8192);

        const f16* pa = lA + cb * 16384 + (wm * 64 + fl) * 64;
        const f16* pb = lB + cb * 8192  + (wn * 64 + fl) * 64;
#pragma unroll
        for (int kk = 0; kk < 2; ++kk) {
            const int o = co ^ (kk << 5);
            f16x8 a[4], b[4];
#pragma unroll
            for (int i = 0; i < 4; ++i)
                a[i] = *(const f16x8*)(pa + i * 1024 + o);
#pragma unroll
            for (int j = 0; j < 4; ++j)
                b[j] = *(const f16x8*)(pb + j * 1024 + o);
            __builtin_amdgcn_s_setprio(1);
#pragma unroll
            for (int i = 0; i < 4; ++i)
#pragma unroll
                for (int j = 0; j < 4; ++j)
                    acc[i][j] = __builtin_amdgcn_mfma_f32_16x16x32_f16(
                        a[i], b[j], acc[i][j], 0, 0, 0);
            __builtin_amdgcn_s_setprio(0);
        }
        cb = cb == 2 ? 0 : cb + 1;
    }
#undef STAGE

    // Epilogue: D[m][n], n = lane&15, m = (lane>>4)*4 + r
    const int rq = (lane >> 4) * 4;
    if (MODE != 0) R += (long)bz * 2048;
#pragma unroll
    for (int i = 0; i < 4; ++i) {
#pragma unroll
        for (int r = 0; r < 4; ++r) {
            const long row = row0 + wm * 64 + i * 16 + rq + r;
            if (MODE == 0) {
#pragma unroll
                for (int j = 0; j < 4; ++j) {
                    const long col = col0 + wn * 64 + j * 16 + fl;
                    C[row * ldc + col] = (OutT)acc[i][j][r];
                }
            } else if (MODE == 1) {
                float s = 0.f;
#pragma unroll
                for (int j = 0; j < 4; ++j) {
                    const long col = col0 + wn * 64 + j * 16 + fl;
                    float e = __expf(acc[i][j][r] * 0.125f - 12.0f);
                    C[row * ldc + col] = (OutT)e;
                    s += e;
                }
                s += __shfl_xor(s, 1, 16);
                s += __shfl_xor(s, 2, 16);
                s += __shfl_xor(s, 4, 16);
                s += __shfl_xor(s, 8, 16);
                if (fl == 0) atomicAdd(&R[row], s);
            } else {
                const float inv = 1.0f / R[row];
#pragma unroll
                for (int j = 0; j < 4; ++j) {
                    const long col = col0 + wn * 64 + j * 16 + fl;
                    C[row * ldc + col] = (OutT)(acc[i][j][r] * inv);
                }
            }
        }
    }
}

__global__ void cvt_f32_f16(const float* __restrict__ in, f16* __restrict__ out,
                            int n4)
{
    int i = blockIdx.x * blockDim.x + threadIdx.x;
    int stride = gridDim.x * blockDim.x;
    for (; i < n4; i += stride) {
        float4 v = ((const float4*)in)[i];
        f16x4 h;
        h[0] = (f16)v.x; h[1] = (f16)v.y; h[2] = (f16)v.z; h[3] = (f16)v.w;
        ((f16x4*)out)[i] = h;
    }
}

// wT[h][o][d] = f16(w[h][d][o]); grid (24, 24, 3), 256 threads (32x8 tile walk)
__global__ void wtrans(const float* __restrict__ w, f16* __restrict__ wT)
{
    __shared__ float t[32][33];
    const int h  = blockIdx.z;
    const int o0 = blockIdx.x * 32, d0 = blockIdx.y * 32;
    const int tx = threadIdx.x & 31, ty = threadIdx.x >> 5;
    const float* src = w + ((size_t)h * 768 + d0) * 768 + o0;
#pragma unroll
    for (int r = 0; r < 32; r += 8)
        t[ty + r][tx] = src[(size_t)(ty + r) * 768 + tx];
    __syncthreads();
    f16* dst = wT + ((size_t)h * 768 + o0) * 768 + d0;
#pragma unroll
    for (int r = 0; r < 32; r += 8)
        dst[(size_t)(ty + r) * 768 + tx] = (f16)t[tx][ty + r];
}

extern "C" void kernel_launch(void* const* d_in, const int* in_sizes, int n_in,
                              void* d_out, int out_size, void* d_ws, size_t ws_size,
                              hipStream_t stream)
{
    (void)in_sizes; (void)n_in; (void)out_size; (void)ws_size;
    const float* x = (const float*)d_in[0];
    const float* w = (const float*)d_in[1];
    float* out = (float*)d_out;

    // B=8, S=2048, D=O=768; BS = 16384
    const long NX = 12582912;      // 16384*768
    const long NW = 1769472;       // 3*768*768
    f16* xh  = (f16*)d_ws;         // [16384][768]   (dead after Vt GEMM)
    f16* wT  = xh + NX;            // [3][768][768]
    f16* QKh = wT + NW;            // [16384][1536]  (Q | K per row)
    f16* Vt  = QKh + 2 * NX;       // [8][768][2048]
    f16* Sc  = Vt + NX;            // [8][2048][2048]  exp-logits (unnormalized)
    float* R = (float*)xh;         // [8][2048] row sums — aliases dead xh
    // total ws: (4*NX + NW + 8*2048*2048) * 2 B = 171,311,104 B

    cvt_f32_f16<<<2048, 256, 0, stream>>>(x, xh, (int)(NX / 4));
    wtrans<<<dim3(24, 24, 3), 256, 0, stream>>>(w, wT);

    // QK = xh @ wT[0..1]^T   (M=16384, N=1536, K=768)
    gemm_bt<0, f16><<<dim3(12, 64, 1), 512, 0, stream>>>(
        xh, wT, QKh, nullptr, 768, 768, 768, 1536, 0, 0, 0);
    // Vt_b = wT2 @ xh_b^T    (M=768, N=2048, K=768), batched over 8
    gemm_bt<0, f16><<<dim3(16, 3, 8), 512, 0, stream>>>(
        wT + 1179648, xh, Vt, nullptr, 768, 768, 768, 2048, 0, 1572864, 1572864);
    // xh dead from here; R aliases it
    hipMemsetAsync(R, 0, 8 * 2048 * sizeof(float), stream);
    // Ps_b = exp(Q_b@K_b^T/8 - 12) + rowsum atomics  (M=2048, N=2048, K=768)
    gemm_bt<1, f16><<<dim3(16, 8, 8), 512, 0, stream>>>(
        QKh, QKh + 768, Sc, R, 768, 1536, 1536, 2048, 3145728, 3145728, 4194304);
    // out_b = (Ps_b @ Vt_b^T) / R[row]  (M=2048, N=768, K=2048), fp32 out
    gemm_bt<2, float><<<dim3(6, 8, 8), 512, 0, stream>>>(
        Sc, Vt, out, R, 2048, 2048, 2048, 768, 4194304, 1572864, 1572864);
}

// Round 3
// 329.290 us; speedup vs baseline: 1.1746x; 1.1746x over previous
//
#include <hip/hip_runtime.h>

// ---------------------------------------------------------------------------
// Self-attention, fp16-MFMA pipeline.
// R8: R7 (m201-style 8-phase 256x256 GEMM core, T2+T3+T4+T5) with the
// swizzle-read bug fixed: second k-half chunk offset is ck0 ^ 32 (XOR, the
// swizzle involution), NOT ck0 + 32 (which walks out of the LDS row for
// lanes with ck0 >= 32 -> garbage fragments -> NaN).
//
//   - BM=BN=256, BK=64, 512 threads = 8 waves (2 wm x 4 wn), per-wave 128x64
//     output as 8 m-frags x 4 n-frags of 16x16 (acc = 128 VGPR).
//   - Interleaved frag mapping: m-frag i -> rows 32i+16wm (A0 = rows 0-127,
//     A1 = 128-255); n-frag j -> cols 64j+16wn (B0/B1 likewise).
//     => each phase reads exactly one A-region and one B-region.
//   - LDS 128 KiB: 2 buffers x (A 32K + B 32K), regions of 16 KiB.
//   - Per K-tile group t (buf cb=t&1): 4 phases, each:
//       {ds_read frags; stage 1 half-tile (2 gload_lds); s_barrier;
//        setprio(1); 16 MFMA; setprio(0); s_barrier}
//     Phase quadrants: (A0,B0),(A0,B1),(A1,B1),(A1,B0).
//     Stage slots:      t+1:A1,  t+1:B0,  t+2:A0,  t+2:B1
//   - Boundary: s_waitcnt vmcnt(4) BEFORE the final barrier (per-wave drain,
//     barrier collects).  The <=4 loads left in flight always belong to
//     K-tile t+2 (next-next), never to data about to be read.
//   - XOR swizzle: LDS row r, 16B-chunk c holds global chunk c ^ (r&7);
//     applied on staging SOURCE address + fragment reads.
// ---------------------------------------------------------------------------

typedef _Float16 f16;
typedef _Float16 f16x8 __attribute__((ext_vector_type(8)));
typedef _Float16 f16x4 __attribute__((ext_vector_type(4)));
typedef float f32x4 __attribute__((ext_vector_type(4)));

__device__ __forceinline__ void gload16(const void* g, void* l) {
    __builtin_amdgcn_global_load_lds((__attribute__((address_space(1))) void*)g,
                                     (__attribute__((address_space(3))) void*)l,
                                     16, 0, 0);
}

// MODE 0: C[row,col] = (OutT)acc
// MODE 1: C = f16(exp(acc/8 - 12)); atomicAdd row sums into R[bz*2048+row]
// MODE 2: C = (OutT)(acc / R[bz*2048+row])
template <int MODE, typename OutT>
__global__ __launch_bounds__(512, 2)
void gemm_bt(const f16* __restrict__ A, const f16* __restrict__ B,
             OutT* __restrict__ C, float* R, int K, int lda, int ldb, int ldc,
             long sA, long sB, long sC)
{
    // [buf][ A0 8192 | A1 8192 | B0 8192 | B1 8192 ] f16 elems, buf stride 32768
    __shared__ __align__(16) f16 lds[65536];

    const int tid  = threadIdx.x;
    const int wave = tid >> 6;
    const int lane = tid & 63;

    // XCD-aware remap (bijection when nb % 8 == 0; all our grids qualify)
    const unsigned gx = gridDim.x, gy = gridDim.y;
    const unsigned nb = gx * gy * gridDim.z;
    unsigned lin = blockIdx.x + gx * (blockIdx.y + gy * blockIdx.z);
    if ((nb & 7u) == 0u) lin = (lin & 7u) * (nb >> 3) + (lin >> 3);
    const unsigned bx = lin % gx;
    const unsigned rem = lin / gx;
    const unsigned by = rem % gy;
    const unsigned bz = rem / gy;

    A += (long)bz * sA;
    B += (long)bz * sB;
    C += (long)bz * sC;

    const long row0 = (long)by * 256;
    const long col0 = (long)bx * 256;

    // Staging: 512 threads; pass covers 64 rows: row = pass*64 + (tid>>3),
    // dst 16B-chunk tid&7, swizzled SOURCE chunk (tid&7) ^ (row&7).
    // Region = 2 passes (128 rows).  LDS dst = region + pass*4096 + tid*8.
    const int r0 = tid >> 3;                       // 0..63
    const int cs = (((tid & 7) ^ (r0 & 7)) * 8);   // swizzled source col (f16)
    const long rsA = (long)lda * 64;
    const long rsB = (long)ldb * 64;
    const f16* gA = A + (row0 + r0) * lda + cs;    // pass-0 base
    const f16* gB = B + (col0 + r0) * ldb + cs;

#define STG_A(buf, half, kt) do {                                             \
        const long ko_ = (long)(kt) * 64;                                     \
        gload16(gA + (2*(half)  )*rsA + ko_,                                  \
                lds + (buf)*32768 + (half)*8192        + tid*8);              \
        gload16(gA + (2*(half)+1)*rsA + ko_,                                  \
                lds + (buf)*32768 + (half)*8192 + 4096 + tid*8);              \
    } while (0)
#define STG_B(buf, half, kt) do {                                             \
        const long ko_ = (long)(kt) * 64;                                     \
        gload16(gB + (2*(half)  )*rsB + ko_,                                  \
                lds + (buf)*32768 + 16384 + (half)*8192        + tid*8);      \
        gload16(gB + (2*(half)+1)*rsB + ko_,                                  \
                lds + (buf)*32768 + 16384 + (half)*8192 + 4096 + tid*8);      \
    } while (0)

    // 8 waves = 2 (wm) x 4 (wn).  Frag rows: 32i+16wm+fl; cols: 64j+16wn+fl.
    const int wm = wave >> 2, wn = wave & 3;
    const int fl = lane & 15;
    const int q  = lane >> 4;
    const int ck0 = ((q ^ (fl & 7)) * 8);          // kk=0 chunk (swizzled)
    const int ck1 = ck0 ^ 32;                      // kk=1 chunk (XOR, not +)
    const int arow = (16 * wm + fl) * 64;          // row base within A region
    const int brow = (16 * wn + fl) * 64;          // row base within B region

    f16x8 a[4][2], b[2][2];
    f32x4 acc[8][4] = {};

#define LDA4(mh, cb) do {                                                     \
        const f16* p_ = lds + (cb)*32768 + (mh)*8192 + arow;                  \
        _Pragma("unroll")                                                     \
        for (int i_ = 0; i_ < 4; ++i_) {                                      \
            a[i_][0] = *(const f16x8*)(p_ + i_*2048 + ck0);                   \
            a[i_][1] = *(const f16x8*)(p_ + i_*2048 + ck1);                   \
        }                                                                     \
    } while (0)
#define LDB2(nh, cb) do {                                                     \
        const f16* p_ = lds + (cb)*32768 + 16384 + (nh)*8192 + brow;          \
        _Pragma("unroll")                                                     \
        for (int j_ = 0; j_ < 2; ++j_) {                                      \
            b[j_][0] = *(const f16x8*)(p_ + j_*4096 + ck0);                   \
            b[j_][1] = *(const f16x8*)(p_ + j_*4096 + ck1);                   \
        }                                                                     \
    } while (0)
#define MFMA16(mh, nh) do {                                                   \
        __builtin_amdgcn_s_setprio(1);                                        \
        _Pragma("unroll")                                                     \
        for (int kk_ = 0; kk_ < 2; ++kk_)                                     \
        _Pragma("unroll")                                                     \
        for (int i_ = 0; i_ < 4; ++i_)                                        \
        _Pragma("unroll")                                                     \
        for (int j_ = 0; j_ < 2; ++j_)                                        \
            acc[(mh)*4 + i_][(nh)*2 + j_] =                                   \
                __builtin_amdgcn_mfma_f32_16x16x32_f16(                       \
                    a[i_][kk_], b[j_][kk_], acc[(mh)*4 + i_][(nh)*2 + j_],    \
                    0, 0, 0);                                                 \
        __builtin_amdgcn_s_setprio(0);                                        \
    } while (0)

    const int nt = K >> 6;

    // Prologue: t0 fully (A0,B1,A1,B0), then t1's A0,B1 -> the last-4-staged
    // loads that vmcnt(4) may leave in flight are t1's A0,B1.
    STG_A(0, 0, 0); STG_B(0, 1, 0); STG_A(0, 1, 0); STG_B(0, 0, 0);
    if (nt > 1) {
        STG_A(1, 0, 1); STG_B(1, 1, 1);
        asm volatile("s_waitcnt vmcnt(4)" ::: "memory");
    } else {
        asm volatile("s_waitcnt vmcnt(0)" ::: "memory");
    }
    __builtin_amdgcn_s_barrier();

    for (int t = 0; t < nt; ++t) {
        const int cb = t & 1, ob = cb ^ 1;
        // ph0: (A0,B0)   stage t+1:A1 (other buf)
        LDA4(0, cb); LDB2(0, cb);
        if (t + 1 < nt) STG_A(ob, 1, t + 1);
        __builtin_amdgcn_s_barrier();
        MFMA16(0, 0);
        __builtin_amdgcn_s_barrier();
        // ph1: (A0,B1)   stage t+1:B0 (other buf)
        LDB2(1, cb);
        if (t + 1 < nt) STG_B(ob, 0, t + 1);
        __builtin_amdgcn_s_barrier();
        MFMA16(0, 1);
        __builtin_amdgcn_s_barrier();
        // ph2: (A1,B1)   stage t+2:A0 (same buf; A0 reads done by ph1's end)
        LDA4(1, cb);
        if (t + 2 < nt) STG_A(cb, 0, t + 2);
        __builtin_amdgcn_s_barrier();
        MFMA16(1, 1);
        __builtin_amdgcn_s_barrier();
        // ph3: (A1,B0)   stage t+2:B1 (same buf; B1 reads done by ph2's end)
        LDB2(0, cb);
        if (t + 2 < nt) STG_B(cb, 1, t + 2);
        __builtin_amdgcn_s_barrier();
        MFMA16(1, 0);
        // Boundary guard for group t+1: drain all but t+2's 4 loads.
        // vmcnt BEFORE barrier: each wave drains its own, barrier collects.
        if (t + 2 < nt) asm volatile("s_waitcnt vmcnt(4)" ::: "memory");
        else            asm volatile("s_waitcnt vmcnt(0)" ::: "memory");
        __builtin_amdgcn_s_barrier();
    }
#undef STG_A
#undef STG_B
#undef LDA4
#undef LDB2
#undef MFMA16

    // Epilogue: D[m][n], n = lane&15, m = (lane>>4)*4 + r
    // row = row0 + 32i + 16wm + rq + r, col = col0 + 64j + 16wn + fl
    const int rq = (lane >> 4) * 4;
    if (MODE != 0) R += (long)bz * 2048;
#pragma unroll
    for (int i = 0; i < 8; ++i) {
#pragma unroll
        for (int r = 0; r < 4; ++r) {
            const long row = row0 + 32 * i + 16 * wm + rq + r;
            if (MODE == 0) {
#pragma unroll
                for (int j = 0; j < 4; ++j) {
                    const long col = col0 + 64 * j + 16 * wn + fl;
                    C[row * ldc + col] = (OutT)acc[i][j][r];
                }
            } else if (MODE == 1) {
                float s = 0.f;
#pragma unroll
                for (int j = 0; j < 4; ++j) {
                    const long col = col0 + 64 * j + 16 * wn + fl;
                    float e = __expf(acc[i][j][r] * 0.125f - 12.0f);
                    C[row * ldc + col] = (OutT)e;
                    s += e;
                }
                s += __shfl_xor(s, 1, 16);
                s += __shfl_xor(s, 2, 16);
                s += __shfl_xor(s, 4, 16);
                s += __shfl_xor(s, 8, 16);
                if (fl == 0) atomicAdd(&R[row], s);
            } else {
                const float inv = 1.0f / R[row];
#pragma unroll
                for (int j = 0; j < 4; ++j) {
                    const long col = col0 + 64 * j + 16 * wn + fl;
                    C[row * ldc + col] = (OutT)(acc[i][j][r] * inv);
                }
            }
        }
    }
}

__global__ void cvt_f32_f16(const float* __restrict__ in, f16* __restrict__ out,
                            int n4)
{
    int i = blockIdx.x * blockDim.x + threadIdx.x;
    int stride = gridDim.x * blockDim.x;
    for (; i < n4; i += stride) {
        float4 v = ((const float4*)in)[i];
        f16x4 h;
        h[0] = (f16)v.x; h[1] = (f16)v.y; h[2] = (f16)v.z; h[3] = (f16)v.w;
        ((f16x4*)out)[i] = h;
    }
}

// wT[h][o][d] = f16(w[h][d][o]); grid (24, 24, 3), 256 threads (32x8 tile walk)
__global__ void wtrans(const float* __restrict__ w, f16* __restrict__ wT)
{
    __shared__ float t[32][33];
    const int h  = blockIdx.z;
    const int o0 = blockIdx.x * 32, d0 = blockIdx.y * 32;
    const int tx = threadIdx.x & 31, ty = threadIdx.x >> 5;
    const float* src = w + ((size_t)h * 768 + d0) * 768 + o0;
#pragma unroll
    for (int r = 0; r < 32; r += 8)
        t[ty + r][tx] = src[(size_t)(ty + r) * 768 + tx];
    __syncthreads();
    f16* dst = wT + ((size_t)h * 768 + o0) * 768 + d0;
#pragma unroll
    for (int r = 0; r < 32; r += 8)
        dst[(size_t)(ty + r) * 768 + tx] = (f16)t[tx][ty + r];
}

extern "C" void kernel_launch(void* const* d_in, const int* in_sizes, int n_in,
                              void* d_out, int out_size, void* d_ws, size_t ws_size,
                              hipStream_t stream)
{
    (void)in_sizes; (void)n_in; (void)out_size; (void)ws_size;
    const float* x = (const float*)d_in[0];
    const float* w = (const float*)d_in[1];
    float* out = (float*)d_out;

    // B=8, S=2048, D=O=768; BS = 16384
    const long NX = 12582912;      // 16384*768
    const long NW = 1769472;       // 3*768*768
    f16* xh  = (f16*)d_ws;         // [16384][768]   (dead after Vt GEMM)
    f16* wT  = xh + NX;            // [3][768][768]
    f16* QKh = wT + NW;            // [16384][1536]  (Q | K per row)
    f16* Vt  = QKh + 2 * NX;       // [8][768][2048]
    f16* Sc  = Vt + NX;            // [8][2048][2048]  exp-logits (unnormalized)
    float* R = (float*)xh;         // [8][2048] row sums — aliases dead xh
    // total ws: (4*NX + NW + 8*2048*2048) * 2 B = 171,311,104 B

    cvt_f32_f16<<<2048, 256, 0, stream>>>(x, xh, (int)(NX / 4));
    wtrans<<<dim3(24, 24, 3), 256, 0, stream>>>(w, wT);

    // QK = xh @ wT[0..1]^T   (M=16384, N=1536, K=768)
    gemm_bt<0, f16><<<dim3(6, 64, 1), 512, 0, stream>>>(
        xh, wT, QKh, nullptr, 768, 768, 768, 1536, 0, 0, 0);
    // Vt_b = wT2 @ xh_b^T    (M=768, N=2048, K=768), batched over 8
    gemm_bt<0, f16><<<dim3(8, 3, 8), 512, 0, stream>>>(
        wT + 1179648, xh, Vt, nullptr, 768, 768, 768, 2048, 0, 1572864, 1572864);
    // xh dead from here; R aliases it
    hipMemsetAsync(R, 0, 8 * 2048 * sizeof(float), stream);
    // Ps_b = exp(Q_b@K_b^T/8 - 12) + rowsum atomics  (M=2048, N=2048, K=768)
    gemm_bt<1, f16><<<dim3(8, 8, 8), 512, 0, stream>>>(
        QKh, QKh + 768, Sc, R, 768, 1536, 1536, 2048, 3145728, 3145728, 4194304);
    // out_b = (Ps_b @ Vt_b^T) / R[row]  (M=2048, N=768, K=2048), fp32 out
    gemm_bt<2, float><<<dim3(3, 8, 8), 512, 0, stream>>>(
        Sc, Vt, out, R, 2048, 2048, 2048, 768, 4194304, 1572864, 1572864);
}

// Round 4
// 326.787 us; speedup vs baseline: 1.1836x; 1.0077x over previous
//
#include <hip/hip_runtime.h>

// ---------------------------------------------------------------------------
// Self-attention, fp16-MFMA pipeline.
// R9: R8's (verified-correct) 256x256 8-phase core with the FULL m201
// derived-waits schedule — the piece R8 was missing:
//   - 2 K-tiles per loop iteration (static buffer indices buf0/buf1).
//   - Stage slots give every load 4-7 phases to land; steady-state
//     per-wave outstanding: 6 -> 14 across 4 phases; vmcnt(6) ONLY at
//     ph3/ph7 ends, retiring exactly the 8 loads of the K-tile about to be
//     read (FIFO vmcnt), leaving {t+2:A0,B1,A1} in flight.
//   - Prologue primes 7 half-tiles: t0 full (A0,B0,A1,B1) + t1:{A0,B1,A1};
//     vmcnt(6) + barrier. ph0 of each iteration stages t+1:B0.
//   - Per phase: {ds_reads; stage 1 half-tile; [lgkmcnt(8) if 12 reads];
//     s_barrier; lgkmcnt(0); setprio(1); 16 MFMA; setprio(0); s_barrier}.
//   - Region-restage provably after last reader's barrier:
//     quadrant walk (A0,B0),(A0,B1),(A1,B1),(A1,B0) frees A0@ph0-end,
//     B1@ph1-end, A1@ph2-end, B0@ph3-end; stages land in those slots.
//   - Tail: iteration with t+2>=nt skips t+2/t+3 stages, vmcnt(0) at ph3
//     (all of t+1 must be resident for ph4-7).  nt even by construction
//     (K=768 -> 12, K=2048 -> 32).
//   - XOR swizzle (verified R8): LDS row r, 16B-chunk c holds global chunk
//     c ^ (r&7); staging SOURCE pre-swizzled; reads use ck0 / ck0^32.
// ---------------------------------------------------------------------------

typedef _Float16 f16;
typedef _Float16 f16x8 __attribute__((ext_vector_type(8)));
typedef _Float16 f16x4 __attribute__((ext_vector_type(4)));
typedef float f32x4 __attribute__((ext_vector_type(4)));

__device__ __forceinline__ void gload16(const void* g, void* l) {
    __builtin_amdgcn_global_load_lds((__attribute__((address_space(1))) void*)g,
                                     (__attribute__((address_space(3))) void*)l,
                                     16, 0, 0);
}

// MODE 0: C[row,col] = (OutT)acc
// MODE 1: C = f16(exp(acc/8 - 12)); atomicAdd row sums into R[bz*2048+row]
// MODE 2: C = (OutT)(acc / R[bz*2048+row])
template <int MODE, typename OutT>
__global__ __launch_bounds__(512, 2)
void gemm_bt(const f16* __restrict__ A, const f16* __restrict__ B,
             OutT* __restrict__ C, float* R, int K, int lda, int ldb, int ldc,
             long sA, long sB, long sC)
{
    // [buf][ A0 8192 | A1 8192 | B0 8192 | B1 8192 ] f16 elems, buf stride 32768
    __shared__ __align__(16) f16 lds[65536];

    const int tid  = threadIdx.x;
    const int wave = tid >> 6;
    const int lane = tid & 63;

    // XCD-aware remap (bijection when nb % 8 == 0; all our grids qualify)
    const unsigned gx = gridDim.x, gy = gridDim.y;
    const unsigned nb = gx * gy * gridDim.z;
    unsigned lin = blockIdx.x + gx * (blockIdx.y + gy * blockIdx.z);
    if ((nb & 7u) == 0u) lin = (lin & 7u) * (nb >> 3) + (lin >> 3);
    const unsigned bx = lin % gx;
    const unsigned rem = lin / gx;
    const unsigned by = rem % gy;
    const unsigned bz = rem / gy;

    A += (long)bz * sA;
    B += (long)bz * sB;
    C += (long)bz * sC;

    const long row0 = (long)by * 256;
    const long col0 = (long)bx * 256;

    // Staging: 512 threads; pass covers 64 rows: row = pass*64 + (tid>>3),
    // dst 16B-chunk tid&7, swizzled SOURCE chunk (tid&7) ^ (row&7).
    // Region = 2 passes (128 rows).  LDS dst = region + pass*4096 + tid*8.
    const int r0 = tid >> 3;                       // 0..63
    const int cs = (((tid & 7) ^ (r0 & 7)) * 8);   // swizzled source col (f16)
    const long rsA = (long)lda * 64;
    const long rsB = (long)ldb * 64;
    const f16* gA = A + (row0 + r0) * lda + cs;    // pass-0 base
    const f16* gB = B + (col0 + r0) * ldb + cs;

#define STG_A(buf, half, kt) do {                                             \
        const long ko_ = (long)(kt) * 64;                                     \
        gload16(gA + (2*(half)  )*rsA + ko_,                                  \
                lds + (buf)*32768 + (half)*8192        + tid*8);              \
        gload16(gA + (2*(half)+1)*rsA + ko_,                                  \
                lds + (buf)*32768 + (half)*8192 + 4096 + tid*8);              \
    } while (0)
#define STG_B(buf, half, kt) do {                                             \
        const long ko_ = (long)(kt) * 64;                                     \
        gload16(gB + (2*(half)  )*rsB + ko_,                                  \
                lds + (buf)*32768 + 16384 + (half)*8192        + tid*8);      \
        gload16(gB + (2*(half)+1)*rsB + ko_,                                  \
                lds + (buf)*32768 + 16384 + (half)*8192 + 4096 + tid*8);      \
    } while (0)

    // 8 waves = 2 (wm) x 4 (wn).  Frag rows: 32i+16wm+fl; cols: 64j+16wn+fl.
    const int wm = wave >> 2, wn = wave & 3;
    const int fl = lane & 15;
    const int q  = lane >> 4;
    const int ck0 = ((q ^ (fl & 7)) * 8);          // kk=0 chunk (swizzled)
    const int ck1 = ck0 ^ 32;                      // kk=1 chunk (XOR involution)
    const int arow = (16 * wm + fl) * 64;          // row base within A region
    const int brow = (16 * wn + fl) * 64;          // row base within B region

    f16x8 a[4][2], b[2][2];
    f32x4 acc[8][4] = {};

#define LDA4(mh, cb) do {                                                     \
        const f16* p_ = lds + (cb)*32768 + (mh)*8192 + arow;                  \
        _Pragma("unroll")                                                     \
        for (int i_ = 0; i_ < 4; ++i_) {                                      \
            a[i_][0] = *(const f16x8*)(p_ + i_*2048 + ck0);                   \
            a[i_][1] = *(const f16x8*)(p_ + i_*2048 + ck1);                   \
        }                                                                     \
    } while (0)
#define LDB2(nh, cb) do {                                                     \
        const f16* p_ = lds + (cb)*32768 + 16384 + (nh)*8192 + brow;          \
        _Pragma("unroll")                                                     \
        for (int j_ = 0; j_ < 2; ++j_) {                                      \
            b[j_][0] = *(const f16x8*)(p_ + j_*4096 + ck0);                   \
            b[j_][1] = *(const f16x8*)(p_ + j_*4096 + ck1);                   \
        }                                                                     \
    } while (0)
#define MFMA16(mh, nh) do {                                                   \
        __builtin_amdgcn_s_setprio(1);                                        \
        _Pragma("unroll")                                                     \
        for (int kk_ = 0; kk_ < 2; ++kk_)                                     \
        _Pragma("unroll")                                                     \
        for (int i_ = 0; i_ < 4; ++i_)                                        \
        _Pragma("unroll")                                                     \
        for (int j_ = 0; j_ < 2; ++j_)                                        \
            acc[(mh)*4 + i_][(nh)*2 + j_] =                                   \
                __builtin_amdgcn_mfma_f32_16x16x32_f16(                       \
                    a[i_][kk_], b[j_][kk_], acc[(mh)*4 + i_][(nh)*2 + j_],    \
                    0, 0, 0);                                                 \
        __builtin_amdgcn_s_setprio(0);                                        \
    } while (0)

#define BAR()   __builtin_amdgcn_s_barrier()
#define LGKM0() asm volatile("s_waitcnt lgkmcnt(0)" ::: "memory")
#define LGKM8() asm volatile("s_waitcnt lgkmcnt(8)" ::: "memory")
#define VM6()   asm volatile("s_waitcnt vmcnt(6)" ::: "memory")
#define VM0()   asm volatile("s_waitcnt vmcnt(0)" ::: "memory")

    const int nt = K >> 6;   // even for all our shapes (12 or 32)

    // Prologue: t0 full (A0,B0,A1,B1 = 8 loads), then t1:{A0,B1,A1} (6).
    // vmcnt(6) retires t0 fully, leaves t1's 6 in flight = steady-state
    // pre-ph0 invariant {t+1:A0,B1,A1}.
    STG_A(0, 0, 0); STG_B(0, 0, 0); STG_A(0, 1, 0); STG_B(0, 1, 0);
    STG_A(1, 0, 1); STG_B(1, 1, 1); STG_A(1, 1, 1);
    VM6();
    BAR();

    for (int t = 0; t < nt; t += 2) {
        const bool s2 = (t + 2 < nt), s3 = (t + 3 < nt);
        // ph0: read t:(A0,B0) [buf0]; stage t+1:B0 -> buf1.B0 (t+1<nt always)
        LDA4(0, 0); LDB2(0, 0);
        STG_B(1, 0, t + 1);
        LGKM8(); BAR(); LGKM0();
        MFMA16(0, 0); BAR();
        // ph1: read t:B1; stage t+2:A0 -> buf0.A0 (t:A0 freed @ph0-end)
        LDB2(1, 0);
        if (s2) STG_A(0, 0, t + 2);
        BAR(); LGKM0();
        MFMA16(0, 1); BAR();
        // ph2: read t:A1; stage t+2:B1 -> buf0.B1 (t:B1 freed @ph1-end)
        LDA4(1, 0);
        if (s2) STG_B(0, 1, t + 2);
        BAR(); LGKM0();
        MFMA16(1, 1); BAR();
        // ph3: read t:B0 (re-read); stage t+2:A1 -> buf0.A1 (freed @ph2-end)
        LDB2(0, 0);
        if (s2) STG_A(0, 1, t + 2);
        BAR(); LGKM0();
        MFMA16(1, 0);
        // retire all of t+1 (read next 4 phases); leave {t+2:A0,B1,A1}
        if (s2) VM6(); else VM0();
        BAR();
        // ph4: read t+1:(A0,B0) [buf1]; stage t+2:B0 -> buf0.B0 (freed @ph3)
        LDA4(0, 1); LDB2(0, 1);
        if (s2) STG_B(0, 0, t + 2);
        LGKM8(); BAR(); LGKM0();
        MFMA16(0, 0); BAR();
        // ph5: read t+1:B1; stage t+3:A0 -> buf1.A0 (t+1:A0 freed @ph4-end)
        LDB2(1, 1);
        if (s3) STG_A(1, 0, t + 3);
        BAR(); LGKM0();
        MFMA16(0, 1); BAR();
        // ph6: read t+1:A1; stage t+3:B1 -> buf1.B1 (t+1:B1 freed @ph5-end)
        LDA4(1, 1);
        if (s3) STG_B(1, 1, t + 3);
        BAR(); LGKM0();
        MFMA16(1, 1); BAR();
        // ph7: read t+1:B0; stage t+3:A1 -> buf1.A1 (t+1:A1 freed @ph6-end)
        LDB2(0, 1);
        if (s3) STG_A(1, 1, t + 3);
        BAR(); LGKM0();
        MFMA16(1, 0);
        // retire all of t+2 (read next 4 phases); leave {t+3:A0,B1,A1}
        if (s3) VM6(); else VM0();
        BAR();
    }
#undef STG_A
#undef STG_B
#undef LDA4
#undef LDB2
#undef MFMA16
#undef BAR
#undef LGKM0
#undef LGKM8
#undef VM6
#undef VM0

    // Epilogue: D[m][n], n = lane&15, m = (lane>>4)*4 + r
    // row = row0 + 32i + 16wm + rq + r, col = col0 + 64j + 16wn + fl
    const int rq = (lane >> 4) * 4;
    if (MODE != 0) R += (long)bz * 2048;
#pragma unroll
    for (int i = 0; i < 8; ++i) {
#pragma unroll
        for (int r = 0; r < 4; ++r) {
            const long row = row0 + 32 * i + 16 * wm + rq + r;
            if (MODE == 0) {
#pragma unroll
                for (int j = 0; j < 4; ++j) {
                    const long col = col0 + 64 * j + 16 * wn + fl;
                    C[row * ldc + col] = (OutT)acc[i][j][r];
                }
            } else if (MODE == 1) {
                float s = 0.f;
#pragma unroll
                for (int j = 0; j < 4; ++j) {
                    const long col = col0 + 64 * j + 16 * wn + fl;
                    float e = __expf(acc[i][j][r] * 0.125f - 12.0f);
                    C[row * ldc + col] = (OutT)e;
                    s += e;
                }
                s += __shfl_xor(s, 1, 16);
                s += __shfl_xor(s, 2, 16);
                s += __shfl_xor(s, 4, 16);
                s += __shfl_xor(s, 8, 16);
                if (fl == 0) atomicAdd(&R[row], s);
            } else {
                const float inv = 1.0f / R[row];
#pragma unroll
                for (int j = 0; j < 4; ++j) {
                    const long col = col0 + 64 * j + 16 * wn + fl;
                    C[row * ldc + col] = (OutT)(acc[i][j][r] * inv);
                }
            }
        }
    }
}

__global__ void cvt_f32_f16(const float* __restrict__ in, f16* __restrict__ out,
                            int n4)
{
    int i = blockIdx.x * blockDim.x + threadIdx.x;
    int stride = gridDim.x * blockDim.x;
    for (; i < n4; i += stride) {
        float4 v = ((const float4*)in)[i];
        f16x4 h;
        h[0] = (f16)v.x; h[1] = (f16)v.y; h[2] = (f16)v.z; h[3] = (f16)v.w;
        ((f16x4*)out)[i] = h;
    }
}

// wT[h][o][d] = f16(w[h][d][o]); grid (24, 24, 3), 256 threads (32x8 tile walk)
__global__ void wtrans(const float* __restrict__ w, f16* __restrict__ wT)
{
    __shared__ float t[32][33];
    const int h  = blockIdx.z;
    const int o0 = blockIdx.x * 32, d0 = blockIdx.y * 32;
    const int tx = threadIdx.x & 31, ty = threadIdx.x >> 5;
    const float* src = w + ((size_t)h * 768 + d0) * 768 + o0;
#pragma unroll
    for (int r = 0; r < 32; r += 8)
        t[ty + r][tx] = src[(size_t)(ty + r) * 768 + tx];
    __syncthreads();
    f16* dst = wT + ((size_t)h * 768 + o0) * 768 + d0;
#pragma unroll
    for (int r = 0; r < 32; r += 8)
        dst[(size_t)(ty + r) * 768 + tx] = (f16)t[tx][ty + r];
}

extern "C" void kernel_launch(void* const* d_in, const int* in_sizes, int n_in,
                              void* d_out, int out_size, void* d_ws, size_t ws_size,
                              hipStream_t stream)
{
    (void)in_sizes; (void)n_in; (void)out_size; (void)ws_size;
    const float* x = (const float*)d_in[0];
    const float* w = (const float*)d_in[1];
    float* out = (float*)d_out;

    // B=8, S=2048, D=O=768; BS = 16384
    const long NX = 12582912;      // 16384*768
    const long NW = 1769472;       // 3*768*768
    f16* xh  = (f16*)d_ws;         // [16384][768]   (dead after Vt GEMM)
    f16* wT  = xh + NX;            // [3][768][768]
    f16* QKh = wT + NW;            // [16384][1536]  (Q | K per row)
    f16* Vt  = QKh + 2 * NX;       // [8][768][2048]
    f16* Sc  = Vt + NX;            // [8][2048][2048]  exp-logits (unnormalized)
    float* R = (float*)xh;         // [8][2048] row sums — aliases dead xh
    // total ws: (4*NX + NW + 8*2048*2048) * 2 B = 171,311,104 B

    cvt_f32_f16<<<2048, 256, 0, stream>>>(x, xh, (int)(NX / 4));
    wtrans<<<dim3(24, 24, 3), 256, 0, stream>>>(w, wT);

    // QK = xh @ wT[0..1]^T   (M=16384, N=1536, K=768)
    gemm_bt<0, f16><<<dim3(6, 64, 1), 512, 0, stream>>>(
        xh, wT, QKh, nullptr, 768, 768, 768, 1536, 0, 0, 0);
    // Vt_b = wT2 @ xh_b^T    (M=768, N=2048, K=768), batched over 8
    gemm_bt<0, f16><<<dim3(8, 3, 8), 512, 0, stream>>>(
        wT + 1179648, xh, Vt, nullptr, 768, 768, 768, 2048, 0, 1572864, 1572864);
    // xh dead from here; R aliases it
    hipMemsetAsync(R, 0, 8 * 2048 * sizeof(float), stream);
    // Ps_b = exp(Q_b@K_b^T/8 - 12) + rowsum atomics  (M=2048, N=2048, K=768)
    gemm_bt<1, f16><<<dim3(8, 8, 8), 512, 0, stream>>>(
        QKh, QKh + 768, Sc, R, 768, 1536, 1536, 2048, 3145728, 3145728, 4194304);
    // out_b = (Ps_b @ Vt_b^T) / R[row]  (M=2048, N=768, K=2048), fp32 out
    gemm_bt<2, float><<<dim3(3, 8, 8), 512, 0, stream>>>(
        Sc, Vt, out, R, 2048, 2048, 2048, 768, 4194304, 1572864, 1572864);
}

// Round 5
// 296.965 us; speedup vs baseline: 1.3025x; 1.1004x over previous
//
#include <hip/hip_runtime.h>

// ---------------------------------------------------------------------------
// Self-attention, fp16-MFMA pipeline.
// R10: revert GEMM core to the PROVEN R5 structure (128x128 tile, BK=64,
// 256 thr / 4 waves, 2-barrier K-loop, global_load_lds(16B), XOR swizzle,
// XCD remap) — best measured 304 us / MODE1 71.5 us.  Two 8-phase ports
// (R8/R9) both landed at 82-85 us MODE1; abandoned.
//
// New in R10: algebraic QK restructuring.
//   QK^T = (X Wq)(X Wk)^T = X (Wq Wk^T) X^T
//   GT   = (Wk @ Wq^T) * SCALE          [768x768]   (gemm_bt of wh1, wh0)
//   XG   = X @ GT^T = X G * SCALE       [16384x768]
//   Ps   = exp(XG_b @ X_b^T - 12)       (MODE 1; scale pre-folded into GT)
// This removes the K-projection (19.3 GFLOP + 25 MB write), shrinks wtrans
// to h=2 only, at the cost of a tiny 36-block 768^3 GEMM.
// All big grids remain exact multiples of 256 CUs (768 / 2048 blocks).
// ---------------------------------------------------------------------------

typedef _Float16 f16;
typedef _Float16 f16x8 __attribute__((ext_vector_type(8)));
typedef _Float16 f16x4 __attribute__((ext_vector_type(4)));
typedef float f32x4 __attribute__((ext_vector_type(4)));

__device__ __forceinline__ void gload16(const void* g, void* l) {
    __builtin_amdgcn_global_load_lds((__attribute__((address_space(1))) void*)g,
                                     (__attribute__((address_space(3))) void*)l,
                                     16, 0, 0);
}

// MODE 0: C[row,col] = (OutT)(acc * oscale)
// MODE 1: C = f16(exp(acc - 12)); atomicAdd row sums into R[bz*2048+row]
// MODE 2: C = (OutT)(acc / R[bz*2048+row])
template <int MODE, typename OutT>
__global__ __launch_bounds__(256, 2)
void gemm_bt(const f16* __restrict__ A, const f16* __restrict__ B,
             OutT* __restrict__ C, float* R, int K, int lda, int ldb, int ldc,
             long sA, long sB, long sC, float oscale)
{
    __shared__ __align__(16) f16 lA[128 * 64];
    __shared__ __align__(16) f16 lB[128 * 64];

    const int tid  = threadIdx.x;
    const int wave = tid >> 6;
    const int lane = tid & 63;

    // XCD-aware remap (bijection when nb % 8 == 0)
    const unsigned gx = gridDim.x, gy = gridDim.y;
    const unsigned nb = gx * gy * gridDim.z;
    unsigned lin = blockIdx.x + gx * (blockIdx.y + gy * blockIdx.z);
    if ((nb & 7u) == 0u) lin = (lin & 7u) * (nb >> 3) + (lin >> 3);
    const unsigned bx = lin % gx;
    const unsigned rem = lin / gx;
    const unsigned by = rem % gy;
    const unsigned bz = rem / gy;

    A += (long)bz * sA;
    B += (long)bz * sB;
    C += (long)bz * sC;

    const long row0 = (long)by * 128;
    const long col0 = (long)bx * 128;

    // Staging: pass p (0..3), LDS chunk = p*256 + tid; row = p*32 + (tid>>3),
    // dst col-chunk = tid&7; SOURCE col-chunk = (tid&7) ^ (row&7).
    const int r0 = tid >> 3;                       // 0..31
    const int cs = (((tid & 7) ^ (r0 & 7)) * 8);   // swizzled source col (f16)
    const f16* ag0 = A + (row0 +      r0) * lda + cs;
    const f16* ag1 = A + (row0 + 32 + r0) * lda + cs;
    const f16* ag2 = A + (row0 + 64 + r0) * lda + cs;
    const f16* ag3 = A + (row0 + 96 + r0) * lda + cs;
    const f16* bg0 = B + (col0 +      r0) * ldb + cs;
    const f16* bg1 = B + (col0 + 32 + r0) * ldb + cs;
    const f16* bg2 = B + (col0 + 64 + r0) * ldb + cs;
    const f16* bg3 = B + (col0 + 96 + r0) * ldb + cs;
    f16* lA0 = lA +        wave * 512;   // pass bases: wave-uniform + lane*16B
    f16* lA1 = lA + 2048 + wave * 512;
    f16* lA2 = lA + 4096 + wave * 512;
    f16* lA3 = lA + 6144 + wave * 512;
    f16* lB0 = lB +        wave * 512;
    f16* lB1 = lB + 2048 + wave * 512;
    f16* lB2 = lB + 4096 + wave * 512;
    f16* lB3 = lB + 6144 + wave * 512;

    // 4 waves in 2x2 -> each wave owns 64x64 = 4x4 MFMA tiles of 16x16.
    const int wm = wave >> 1, wn = wave & 1;
    const int fl = lane & 15;            // m (A) / n (B) within tile
    const int q  = lane >> 4;            // k-chunk within 32-k half
    // fragment read: row*64 + ((g ^ (row&7)) * 8); row&7 == fl&7.
    // kk=0: g=q -> co; kk=32: g=q^4 -> co^32.
    const int co = ((q ^ (fl & 7)) * 8);
    const f16* paw = lA + (wm * 64 + fl) * 64;
    const f16* pbw = lB + (wn * 64 + fl) * 64;

    f32x4 acc[4][4] = {};

    for (int k0 = 0; k0 < K; k0 += 64) {
        __syncthreads();                 // LDS free from previous iteration
        gload16(ag0, lA0); gload16(ag1, lA1);
        gload16(ag2, lA2); gload16(ag3, lA3);
        gload16(bg0, lB0); gload16(bg1, lB1);
        gload16(bg2, lB2); gload16(bg3, lB3);
        ag0 += 64; ag1 += 64; ag2 += 64; ag3 += 64;
        bg0 += 64; bg1 += 64; bg2 += 64; bg3 += 64;
        __syncthreads();                 // drains vmcnt -> staged data visible

#pragma unroll
        for (int kk = 0; kk < 64; kk += 32) {
            const int o = co ^ (kk == 0 ? 0 : 32);
            f16x8 a[4], b[4];
#pragma unroll
            for (int i = 0; i < 4; ++i)
                a[i] = *(const f16x8*)(paw + i * 1024 + o);
#pragma unroll
            for (int j = 0; j < 4; ++j)
                b[j] = *(const f16x8*)(pbw + j * 1024 + o);
#pragma unroll
            for (int i = 0; i < 4; ++i)
#pragma unroll
                for (int j = 0; j < 4; ++j)
                    acc[i][j] = __builtin_amdgcn_mfma_f32_16x16x32_f16(
                        a[i], b[j], acc[i][j], 0, 0, 0);
        }
    }

    // Epilogue: D[m][n], n = lane&15, m = (lane>>4)*4 + r
    const int rq = (lane >> 4) * 4;
    if (MODE != 0) R += (long)bz * 2048;
#pragma unroll
    for (int i = 0; i < 4; ++i) {
#pragma unroll
        for (int r = 0; r < 4; ++r) {
            const long row = row0 + wm * 64 + i * 16 + rq + r;
            if (MODE == 0) {
#pragma unroll
                for (int j = 0; j < 4; ++j) {
                    const long col = col0 + wn * 64 + j * 16 + fl;
                    C[row * ldc + col] = (OutT)(acc[i][j][r] * oscale);
                }
            } else if (MODE == 1) {
                float s = 0.f;
#pragma unroll
                for (int j = 0; j < 4; ++j) {
                    const long col = col0 + wn * 64 + j * 16 + fl;
                    float e = __expf(acc[i][j][r] - 12.0f);   // scale in GT
                    C[row * ldc + col] = (OutT)e;
                    s += e;
                }
                s += __shfl_xor(s, 1, 16);
                s += __shfl_xor(s, 2, 16);
                s += __shfl_xor(s, 4, 16);
                s += __shfl_xor(s, 8, 16);
                if (fl == 0) atomicAdd(&R[row], s);
            } else {
                const float inv = 1.0f / R[row];
#pragma unroll
                for (int j = 0; j < 4; ++j) {
                    const long col = col0 + wn * 64 + j * 16 + fl;
                    C[row * ldc + col] = (OutT)(acc[i][j][r] * inv);
                }
            }
        }
    }
}

__global__ void cvt_f32_f16(const float* __restrict__ in, f16* __restrict__ out,
                            int n4)
{
    int i = blockIdx.x * blockDim.x + threadIdx.x;
    int stride = gridDim.x * blockDim.x;
    for (; i < n4; i += stride) {
        float4 v = ((const float4*)in)[i];
        f16x4 h;
        h[0] = (f16)v.x; h[1] = (f16)v.y; h[2] = (f16)v.z; h[3] = (f16)v.w;
        ((f16x4*)out)[i] = h;
    }
}

// wT[o][d] = f16(w[d][o]) for ONE 768x768 matrix; grid (24, 24), 256 threads
__global__ void wtrans(const float* __restrict__ w, f16* __restrict__ wT)
{
    __shared__ float t[32][33];
    const int o0 = blockIdx.x * 32, d0 = blockIdx.y * 32;
    const int tx = threadIdx.x & 31, ty = threadIdx.x >> 5;
    const float* src = w + (size_t)d0 * 768 + o0;
#pragma unroll
    for (int r = 0; r < 32; r += 8)
        t[ty + r][tx] = src[(size_t)(ty + r) * 768 + tx];
    __syncthreads();
    f16* dst = wT + (size_t)o0 * 768 + d0;
#pragma unroll
    for (int r = 0; r < 32; r += 8)
        dst[(size_t)(ty + r) * 768 + tx] = (f16)t[tx][ty + r];
}

extern "C" void kernel_launch(void* const* d_in, const int* in_sizes, int n_in,
                              void* d_out, int out_size, void* d_ws, size_t ws_size,
                              hipStream_t stream)
{
    (void)in_sizes; (void)n_in; (void)out_size; (void)ws_size;
    const float* x = (const float*)d_in[0];
    const float* w = (const float*)d_in[1];
    float* out = (float*)d_out;

    // B=8, S=2048, D=O=768; BS = 16384
    const long NX = 12582912;      // 16384*768
    const long NW = 1769472;       // 3*768*768
    const long NW1 = 589824;       // 768*768
    f16* xh  = (f16*)d_ws;         // [16384][768]   X  (alive thru MODE1)
    f16* wh  = xh + NX;            // [3][768][768]  f16(w), dead after GT
    f16* wt2 = wh + NW;            // [768][768]     Wv^T, dead after Vt
    f16* GT  = wt2 + NW1;          // [768][768]     (Wk Wq^T)*SCALE
    f16* XG  = GT + NW1;           // [16384][768]   X G * SCALE
    f16* Vt  = XG + NX;            // [8][768][2048]
    f16* Sc  = Vt + NX;            // [8][2048][2048] exp-logits (unnormalized)
    float* R = (float*)wh;         // [8][2048] row sums — aliases dead wh
    // total ws: (3*NX + NW + 2*NW1 + 8*2048*2048) * 2 B = 148,504,576 B

    cvt_f32_f16<<<2048, 256, 0, stream>>>(x, xh, (int)(NX / 4));
    cvt_f32_f16<<<1024, 256, 0, stream>>>(w, wh, (int)(NW / 4));
    // wt2[o][d] = f16(w[2][d][o])
    wtrans<<<dim3(24, 24, 1), 256, 0, stream>>>(w + 2 * NW1, wt2);

    // GT = (wh1 @ wh0^T) * SCALE : GT[i][j] = sum_o Wk[i][o] Wq[j][o] / 8
    gemm_bt<0, f16><<<dim3(6, 6, 1), 256, 0, stream>>>(
        wh + NW1, wh, GT, nullptr, 768, 768, 768, 768, 0, 0, 0, 0.125f);
    // XG = xh @ GT^T : XG[s][o] = sum_k X[s][k] G[k][o] / 8   (M=16384,N=768)
    gemm_bt<0, f16><<<dim3(6, 128, 1), 256, 0, stream>>>(
        xh, GT, XG, nullptr, 768, 768, 768, 768, 0, 0, 0, 1.0f);
    // Vt_b = wt2 @ xh_b^T    (M=768, N=2048, K=768), batched over 8
    gemm_bt<0, f16><<<dim3(16, 6, 8), 256, 0, stream>>>(
        wt2, xh, Vt, nullptr, 768, 768, 768, 2048, 0, 1572864, 1572864, 1.0f);
    // wh dead from here; R aliases it
    hipMemsetAsync(R, 0, 8 * 2048 * sizeof(float), stream);
    // Ps_b = exp(XG_b @ xh_b^T - 12) + rowsum atomics (M=2048,N=2048,K=768)
    gemm_bt<1, f16><<<dim3(16, 16, 8), 256, 0, stream>>>(
        XG, xh, Sc, R, 768, 768, 768, 2048, 1572864, 1572864, 4194304, 1.0f);
    // out_b = (Ps_b @ Vt_b^T) / R[row]  (M=2048, N=768, K=2048), fp32 out
    gemm_bt<2, float><<<dim3(6, 16, 8), 256, 0, stream>>>(
        Sc, Vt, out, R, 2048, 2048, 2048, 768, 4194304, 1572864, 1572864, 1.0f);
}